// Round 13
// baseline (247.876 us; speedup 1.0000x reference)
//
#include <hip/hip_runtime.h>
#include <hip/hip_bf16.h>

// Detect head: prep (fp32->bf16 convert + x transpose) then fused MFMA GEMM + decode.
// R13 = R12 with the K-loop decoupled from global->LDS staging:
//   - A operand: global -> REGISTERS (a8[2][8], 16x16B per lane, L2-hot via
//     mtile-major XCD swizzle kept from R8/R12). No A-LDS at all.
//   - B operand: staged ONCE per 256-K half as 4 subtiles of R12's proven
//     [96][64] pitch-128B XOR-swizzled layout (48KB LDS).
//   - K-loop: 3 ds_read_b128 + 6 MFMA per kk, ZERO barriers/drains inside.
//     Block total: 2 barriers (lvl0) / 3 (lvl1) vs R12's per-kt drains.
//   - Epilogue, nt-stores, prep kernels, grid: identical to R12.

typedef __attribute__((ext_vector_type(8))) short short8;
typedef __attribute__((ext_vector_type(4))) short short4v;
typedef __attribute__((ext_vector_type(4))) float f32x4;
typedef unsigned int u32;

__device__ __forceinline__ unsigned short f2bf(float f) {
    union { float f; unsigned u; } c; c.f = f;
    return (unsigned short)((c.u + 0x7fffu + ((c.u >> 16) & 1u)) >> 16);  // RTNE
}
__device__ __forceinline__ float sigm(float v) {
    return 1.0f / (1.0f + __expf(-v));
}
__device__ __forceinline__ void gload16(const void* g, void* l) {
    __builtin_amdgcn_global_load_lds(
        (const __attribute__((address_space(1))) u32*)g,
        (__attribute__((address_space(3))) u32*)l, 16, 0, 0);
}

#define OUT_CH 1548
#define NCHN   86
#define BPB    7925760   // per-batch output elements = 92160*86

// ---------------- prep kernels ----------------

__global__ void conv_w_kernel(const float* __restrict__ W0, unsigned short* __restrict__ Wb0,
                              const float* __restrict__ W1, unsigned short* __restrict__ Wb1) {
    int i = blockIdx.x * blockDim.x + threadIdx.x;
    if (i >= 297216) return;
    const float* W = W0;
    unsigned short* Wb = Wb0;
    if (i >= 99072) { W = W1; Wb = Wb1; i -= 99072; }
    const float4 f = ((const float4*)W)[i];
    short4v v;
    v[0] = (short)f2bf(f.x); v[1] = (short)f2bf(f.y);
    v[2] = (short)f2bf(f.z); v[3] = (short)f2bf(f.w);
    ((short4v*)Wb)[i] = v;
}

// x [B][C][GG] fp32 -> Xb [B][GG][C] bf16 (64x64 LDS tile transpose)
__global__ void transpose_x_kernel(const float* __restrict__ X, unsigned short* __restrict__ Xb,
                                   int C, int GG) {
    __shared__ float sT[64][65];
    const int p0 = blockIdx.x * 64;
    const int c0 = blockIdx.y * 64;
    const int b  = blockIdx.z;
    const int tid = threadIdx.x;
    const float* src = X + ((size_t)b * C + c0) * GG + p0;
    const int rc = tid >> 4;
    const int cp = (tid & 15) * 4;
    #pragma unroll
    for (int rr = 0; rr < 4; ++rr) {
        const int c = rc + rr * 16;
        const float4 f = *(const float4*)&src[(size_t)c * GG + cp];
        sT[c][cp + 0] = f.x; sT[c][cp + 1] = f.y;
        sT[c][cp + 2] = f.z; sT[c][cp + 3] = f.w;
    }
    __syncthreads();
    const int p  = tid >> 2;
    const int cg = (tid & 3) * 16;
    unsigned short u[16];
    #pragma unroll
    for (int k = 0; k < 16; ++k) u[k] = f2bf(sT[cg + k][p]);
    unsigned short* dst = Xb + ((size_t)b * GG + p0 + p) * C + c0 + cg;
    *(short8*)dst       = *(const short8*)&u[0];
    *(short8*)(dst + 8) = *(const short8*)&u[8];
}

// ---------------- main GEMM + decode ----------------

__global__ __launch_bounds__(256, 3) void detect_gemm(
    const unsigned short* __restrict__ Xb0, const unsigned short* __restrict__ Xb1,
    const unsigned short* __restrict__ Wb0, const unsigned short* __restrict__ Wb1,
    const float* __restrict__ b0, const float* __restrict__ b1,
    float* __restrict__ out)
{
    // LDS 48KB: B = 4 subtiles x [96 rows][64 k] bf16 (12KB each, pitch 128B,
    // XOR-swizzled). Epilogue reuses first 22KB as flat [64*86] fp32 image.
    // 3 blocks/CU.
    __shared__ __attribute__((aligned(128))) char smem[49152];
    float* sOutF = (float*)smem;

    // XCD swizzle (mtile-major, R8/R12): 11520 = 8 * 1440; consecutive v within
    // an XCD share the same mtile across 18 anchors -> A rows L2-hit 17x.
    const int bid = blockIdx.x;
    const int v   = (bid & 7) * 1440 + (bid >> 3);
    const int mt  = v / 18;           // mtile 0..639
    const int a   = v - mt * 18;      // anchor 0..17

    const bool lvl1 = (mt >= 512);
    const unsigned short* __restrict__ Xb = lvl1 ? Xb1 : Xb0;
    const unsigned short* __restrict__ Wb = lvl1 ? Wb1 : Wb0;
    const float* __restrict__ biasA = (lvl1 ? b1 : b0) + a * NCHN;
    const int C   = lvl1 ? 512 : 256;
    const int GG  = lvl1 ? 1024 : 4096;
    const int Gsh = lvl1 ? 5 : 6;
    const float sxy     = lvl1 ? 1.1f : 1.2f;
    const float sxy_off = (sxy - 1.0f) * 0.5f;
    const float sf      = lvl1 ? 16.0f : 8.0f;
    const int shp  = a / 6;
    const int angi = a - shp * 6;
    const float aw = lvl1 ? ((shp == 0) ? 30.f : (shp == 1) ? 62.f : 59.f)
                          : ((shp == 0) ? 10.f : (shp == 1) ? 16.f : 33.f);
    const float ah = lvl1 ? ((shp == 0) ? 61.f : (shp == 1) ? 45.f : 119.f)
                          : ((shp == 0) ? 13.f : (shp == 1) ? 30.f : 23.f);
    const float aa = (angi == 0) ? -1.04719755119659775f :
                     (angi == 1) ? -0.52359877559829887f :
                     (angi == 2) ?  0.0f :
                     (angi == 3) ?  0.52359877559829887f :
                     (angi == 4) ?  1.04719755119659775f :
                                    1.57079632679489662f;

    const int tloc = lvl1 ? (mt - 512) : mt;
    const int b  = tloc >> (lvl1 ? 4 : 6);               // tiles/img: 16 / 64
    const int p0 = (tloc & ((lvl1 ? 16 : 64) - 1)) * 64; // pixel offset

    const int tid  = threadIdx.x;
    const int lane = tid & 63;
    const int wid  = tid >> 6;        // 0..3
    const int wm = wid >> 1;          // 0..1 : 32-pixel slice
    const int wn = wid & 1;           // 0..1 : 48-channel half

    f32x4 acc[2][3];
    #pragma unroll
    for (int i = 0; i < 2; ++i)
        #pragma unroll
        for (int j = 0; j < 3; ++j)
            acc[i][j] = f32x4{0.f, 0.f, 0.f, 0.f};

    // ---- B staging geometry (per 64-k subtile, pitch 128B, R12-proven) ----
    const int rowIn = lane >> 3;                                  // 0..7
    const int scolE = ((((lane & 7) << 4)) ^ (rowIn << 4)) >> 1;  // element col in source

    const int lr   = lane & 15;
    const int kqb  = (lane >> 4) << 4;        // k-quarter byte offset in 64B half-row
    const int swzR = (lr & 7) << 4;           // read-side XOR
    const int kb16 = kqb;                     // A: same k-quarter byte offset

    // stage 4 subtiles covering k in [k0, k0+256): 12 gload16 per thread
    auto stageB = [&](int k0) {
        #pragma unroll
        for (int s = 0; s < 4; ++s) {
            #pragma unroll
            for (int j = 0; j < 3; ++j) {
                const int c = j * 4 + wid;
                const int row = c * 8 + rowIn;                 // 0..95
                int grow = a * NCHN + row;
                grow = grow > (OUT_CH - 1) ? (OUT_CH - 1) : grow;
                gload16(Wb + (size_t)grow * C + k0 + s * 64 + scolE,
                        smem + s * 12288 + (c << 10));
            }
        }
    };

    // ---- A register loads: lane holds rows (wm*32 + i*16 + lr), 8 k-frags ----
    const char* ApBase = (const char*)(Xb + ((size_t)b * GG + p0 + wm * 32 + lr) * C);
    const size_t Arow16 = (size_t)16 * C * 2;   // byte stride for i=1
    short8 a8[2][8];
    auto loadA = [&](int k0) {
        #pragma unroll
        for (int i = 0; i < 2; ++i)
            #pragma unroll
            for (int kk = 0; kk < 8; ++kk)
                a8[i][kk] = *(const short8*)(ApBase + i * Arow16 + (size_t)k0 * 2 + kk * 64 + kb16);
    };

    auto computeHalf = [&]() {
        #pragma unroll
        for (int kk = 0; kk < 8; ++kk) {
            const int s  = kk >> 1;
            const int cb = ((kk & 1) << 6) + kqb;
            short8 bfr[3];
            #pragma unroll
            for (int j = 0; j < 3; ++j) {
                const int rb = wn * 48 + j * 16 + lr;
                bfr[j] = *(const short8*)(smem + s * 12288 + rb * 128 + (cb ^ swzR));
            }
            #pragma unroll
            for (int i = 0; i < 2; ++i)
                #pragma unroll
                for (int j = 0; j < 3; ++j)
                    acc[i][j] = __builtin_amdgcn_mfma_f32_16x16x32_bf16(a8[i][kk], bfr[j], acc[i][j], 0, 0, 0);
        }
    };

    // ---- barrier-light main loop ----
    loadA(0);
    stageB(0);
    __syncthreads();        // single drain: B (and A regs) landed
    computeHalf();
    if (lvl1) {
        __syncthreads();    // all waves done reading B half 1
        loadA(256);
        stageB(256);
        __syncthreads();    // half-2 staged
        computeHalf();
    }
    __syncthreads();        // all B reads done before LDS reuse as sOutF

    // ---- epilogue: decode into flat LDS image [64 px][86 ch], then stream out ----
    // C/D layout: col(N)=lane&15, row(M)=(lane>>4)*4+reg
    const int rq = (lane >> 4) * 4;
    const int lvloff = lvl1 ? 73728 : 0;

    #pragma unroll
    for (int j = 0; j < 3; ++j) {
        const int ch = wn * 48 + j * 16 + lr;
        if (ch < NCHN) {
            const float bv = biasA[ch];
            #pragma unroll
            for (int i = 0; i < 2; ++i) {
                #pragma unroll
                for (int r = 0; r < 4; ++r) {
                    const int px = wm * 32 + i * 16 + rq + r;   // 0..63
                    const int p  = p0 + px;                     // pixel in level grid
                    const float vv = acc[i][j][r] + bv;
                    float res;
                    if (ch == 0)      res = (sigm(vv) * sxy - sxy_off + (float)(p & ((1 << Gsh) - 1))) * sf;
                    else if (ch == 1) res = (sigm(vv) * sxy - sxy_off + (float)(p >> Gsh)) * sf;
                    else if (ch == 2) res = __expf(vv) * aw;
                    else if (ch == 3) res = __expf(vv) * ah;
                    else if (ch == 4) res = vv + aa;
                    else              res = sigm(vv);
                    sOutF[px * NCHN + ch] = res;
                }
            }
        }
    }
    __syncthreads();

    // stream out: block span = 64*86 = 5504 dwords, contiguous & 16B-aligned.
    // Non-temporal: write-once data, bypass L2 allocation.
    const size_t spanDw = (size_t)b * BPB + ((size_t)(lvloff + a * GG + p0)) * NCHN;
    #pragma unroll
    for (int k = 0; k < 6; ++k) {
        const int f4 = tid + k * 256;       // float4 index, 1376 total
        if (f4 < 1376) {
            const f32x4 vv = *(const f32x4*)&sOutF[f4 * 4];
            __builtin_nontemporal_store(vv, (f32x4*)&out[spanDw + f4 * 4]);
        }
    }
}

extern "C" void kernel_launch(void* const* d_in, const int* in_sizes, int n_in,
                              void* d_out, int out_size, void* d_ws, size_t ws_size,
                              hipStream_t stream) {
    const float* x0 = (const float*)d_in[0];
    const float* x1 = (const float*)d_in[1];
    const float* W0 = (const float*)d_in[2];
    const float* b0 = (const float*)d_in[3];
    const float* W1 = (const float*)d_in[4];
    const float* b1 = (const float*)d_in[5];
    float* out = (float*)d_out;

    constexpr size_t XB0_OFF = 0;            // 8*4096*256*2  = 16777216
    constexpr size_t XB1_OFF = 16777216;     // 8*1024*512*2  =  8388608
    constexpr size_t WB0_OFF = 25165824;     // 1548*256*2    =   792576
    constexpr size_t WB1_OFF = 25958400;     // 1548*512*2    =  1585152

    unsigned short* Xb0 = (unsigned short*)((char*)d_ws + XB0_OFF);
    unsigned short* Xb1 = (unsigned short*)((char*)d_ws + XB1_OFF);
    unsigned short* Wb0 = (unsigned short*)((char*)d_ws + WB0_OFF);
    unsigned short* Wb1 = (unsigned short*)((char*)d_ws + WB1_OFF);

    hipLaunchKernelGGL(conv_w_kernel, dim3((297216 + 255) / 256), dim3(256), 0, stream,
                       W0, Wb0, W1, Wb1);
    hipLaunchKernelGGL(transpose_x_kernel, dim3(64, 4, 8), dim3(256), 0, stream,
                       x0, Xb0, 256, 4096);
    hipLaunchKernelGGL(transpose_x_kernel, dim3(16, 8, 8), dim3(256), 0, stream,
                       x1, Xb1, 512, 1024);

    // 640 mtiles (512 lvl0 + 128 lvl1) x 18 anchors = 11520 blocks
    hipLaunchKernelGGL(detect_gemm, dim3(11520), dim3(256), 0, stream,
                       Xb0, Xb1, Wb0, Wb1, b0, b1, out);
}

// Round 14
// 186.396 us; speedup vs baseline: 1.3298x; 1.3298x over previous
//
#include <hip/hip_runtime.h>
#include <hip/hip_bf16.h>

// Detect head: prep (fp32->bf16 convert + x transpose) then fused MFMA GEMM + decode.
// R14: multi-anchor blocks to cut staged L2 traffic 2.4x (the measured binding
// constraint of R8-R13, all stuck ~120us at ~1.1GB staged):
//   - Block = one mtile (128px lvl0 / 64px lvl1) x 9 anchors (aBase..aBase+8).
//   - A tile [BM][C] staged ONCE per block into LDS (64KB, XOR-swizzled via
//     pre-swizzled gload source). A traffic: 454 -> 50 MB.
//   - B tile per (anchor,kt): [128pad][64k] 16KB, double-buffered, staged with
//     EXACTLY 2 gload_lds/thread -> counted s_waitcnt vmcnt(2) + raw s_barrier
//     (T4). Bias pre-staged to LDS so no stray VMEM breaks the vmcnt count.
//   - Per-anchor epilogue: decode -> LDS image -> contiguous nt f32x4 stores;
//     drains own stores with vmcnt(2) leaving the B prefetch in flight.
//   - 768 blocks (equal FLOP each), 512 threads, 142KB LDS (1 block/CU).

typedef __attribute__((ext_vector_type(8))) short short8;
typedef __attribute__((ext_vector_type(4))) short short4v;
typedef __attribute__((ext_vector_type(4))) float f32x4;
typedef unsigned int u32;

__device__ __forceinline__ unsigned short f2bf(float f) {
    union { float f; unsigned u; } c; c.f = f;
    return (unsigned short)((c.u + 0x7fffu + ((c.u >> 16) & 1u)) >> 16);  // RTNE
}
__device__ __forceinline__ float sigm(float v) {
    return 1.0f / (1.0f + __expf(-v));
}
__device__ __forceinline__ void gload16(const void* g, void* l) {
    __builtin_amdgcn_global_load_lds(
        (const __attribute__((address_space(1))) u32*)g,
        (__attribute__((address_space(3))) u32*)l, 16, 0, 0);
}

#define OUT_CH 1548
#define NCHN   86
#define BPB    7925760   // per-batch output elements = 92160*86

// ---------------- prep kernels ----------------

__global__ void conv_w_kernel(const float* __restrict__ W0, unsigned short* __restrict__ Wb0,
                              const float* __restrict__ W1, unsigned short* __restrict__ Wb1) {
    int i = blockIdx.x * blockDim.x + threadIdx.x;
    if (i >= 297216) return;
    const float* W = W0;
    unsigned short* Wb = Wb0;
    if (i >= 99072) { W = W1; Wb = Wb1; i -= 99072; }
    const float4 f = ((const float4*)W)[i];
    short4v v;
    v[0] = (short)f2bf(f.x); v[1] = (short)f2bf(f.y);
    v[2] = (short)f2bf(f.z); v[3] = (short)f2bf(f.w);
    ((short4v*)Wb)[i] = v;
}

// x [B][C][GG] fp32 -> Xb [B][GG][C] bf16 (64x64 LDS tile transpose)
__global__ void transpose_x_kernel(const float* __restrict__ X, unsigned short* __restrict__ Xb,
                                   int C, int GG) {
    __shared__ float sT[64][65];
    const int p0 = blockIdx.x * 64;
    const int c0 = blockIdx.y * 64;
    const int b  = blockIdx.z;
    const int tid = threadIdx.x;
    const float* src = X + ((size_t)b * C + c0) * GG + p0;
    const int rc = tid >> 4;
    const int cp = (tid & 15) * 4;
    #pragma unroll
    for (int rr = 0; rr < 4; ++rr) {
        const int c = rc + rr * 16;
        const float4 f = *(const float4*)&src[(size_t)c * GG + cp];
        sT[c][cp + 0] = f.x; sT[c][cp + 1] = f.y;
        sT[c][cp + 2] = f.z; sT[c][cp + 3] = f.w;
    }
    __syncthreads();
    const int p  = tid >> 2;
    const int cg = (tid & 3) * 16;
    unsigned short u[16];
    #pragma unroll
    for (int k = 0; k < 16; ++k) u[k] = f2bf(sT[cg + k][p]);
    unsigned short* dst = Xb + ((size_t)b * GG + p0 + p) * C + c0 + cg;
    *(short8*)dst       = *(const short8*)&u[0];
    *(short8*)(dst + 8) = *(const short8*)&u[8];
}

// ---------------- main GEMM + decode ----------------

__global__ __launch_bounds__(512, 1) void detect_gemm(
    const unsigned short* __restrict__ Xb0, const unsigned short* __restrict__ Xb1,
    const unsigned short* __restrict__ Wb0, const unsigned short* __restrict__ Wb1,
    const float* __restrict__ b0, const float* __restrict__ b1,
    float* __restrict__ out)
{
    // LDS map: [0,64K) A tile | [64K,96K) B dbuf 2x16KB | [96K,96K+43K) image |
    //          [139.5K, +3.1K) bias for 9 anchors. Total ~142.5KB.
    __shared__ __attribute__((aligned(128))) char smem[145472];
    float* sOutF = (float*)(smem + 98304);
    float* sBias = (float*)(smem + 142336);   // 774 floats

    // XCD swizzle: 768 = 8 * 96 (bijective). Consecutive v in an XCD = same
    // mtile's two anchor-groups, then next mtile -> A region L2-hot.
    const int bid = blockIdx.x;
    const int v   = (bid & 7) * 96 + (bid >> 3);
    const bool lvl1 = (v >= 512);

    int b, p0, grp;
    if (!lvl1) { const int m = v >> 1;        grp = v & 1;  b = m >> 5; p0 = (m & 31) * 128; }
    else       { const int u = (v - 512) >> 1; grp = v & 1; b = u >> 4; p0 = (u & 15) * 64; }
    const int aBase = grp * 9;

    const unsigned short* __restrict__ Xb = lvl1 ? Xb1 : Xb0;
    const unsigned short* __restrict__ Wb = lvl1 ? Wb1 : Wb0;
    const float* __restrict__ bias = lvl1 ? b1 : b0;
    const int C     = lvl1 ? 512 : 256;
    const int GG    = lvl1 ? 1024 : 4096;
    const int Gsh   = lvl1 ? 5 : 6;
    const int KT    = lvl1 ? 8 : 4;
    const int ktsh  = lvl1 ? 3 : 2;
    const int ktMask= KT - 1;
    const int pitch = C * 2;                  // A row pitch in bytes
    const int MI    = lvl1 ? 1 : 2;           // A m-frags per wave
    const int MROWS = lvl1 ? 16 : 32;         // wave pixel span
    const float sxy     = lvl1 ? 1.1f : 1.2f;
    const float sxy_off = (sxy - 1.0f) * 0.5f;
    const float sf      = lvl1 ? 16.0f : 8.0f;
    const int lvloff    = lvl1 ? 73728 : 0;

    const int tid  = threadIdx.x;
    const int lane = tid & 63;
    const int wid  = tid >> 6;        // 0..7
    const int wm = wid >> 1;          // 0..3 : pixel slice
    const int wn = wid & 1;           // 0..1 : 48-channel half

    // ---- bias -> LDS (before any pipelined loads; compiler waits locally) ----
    #pragma unroll
    for (int k = 0; k < 2; ++k) {
        const int idx = tid + k * 512;
        if (idx < 9 * NCHN) sBias[idx] = bias[aBase * NCHN + idx];
    }

    f32x4 acc[2][3];
    #pragma unroll
    for (int i = 0; i < 2; ++i)
        #pragma unroll
        for (int j = 0; j < 3; ++j)
            acc[i][j] = f32x4{0.f, 0.f, 0.f, 0.f};

    // ---- A staging geometry (64KB, 8 issues x 512thr x 16B) ----
    const int rowAin = lvl1 ? (tid >> 6) : (tid >> 5);
    const int colbA  = (lvl1 ? (tid & 63) : (tid & 31)) << 4;
    const int scolAe = (colbA ^ ((rowAin & 7) << 4)) >> 1;
    const int rpiA   = lvl1 ? 8 : 16;
    const unsigned short* __restrict__ Xp = Xb + ((size_t)b * GG + p0) * C;

    // ---- B staging geometry (16KB padded tile, 2 issues/thread) ----
    const int rowInB = lane >> 3;
    const int scolBe = (((lane & 7) << 4) ^ (rowInB << 4)) >> 1;

    const int lr   = lane & 15;
    const int kqb  = (lane >> 4) << 4;
    const int swzR = (lr & 7) << 4;

    int rowAb[2], rowBb[3];
    #pragma unroll
    for (int i = 0; i < 2; ++i) rowAb[i] = (wm * MROWS + i * 16 + lr) * pitch;
    #pragma unroll
    for (int j = 0; j < 3; ++j) rowBb[j] = (wn * 48 + j * 16 + lr) * 128;

    auto stageB = [&](int s) {
        const int aL = s >> ktsh;
        const int kt = s & ktMask;
        const int k0 = kt << 6;
        const int ag = aBase + aL;
        char* dst = smem + 65536 + (s & 1) * 16384;
        #pragma unroll
        for (int j = 0; j < 2; ++j) {
            const int c = j * 8 + wid;
            const int row = c * 8 + rowInB;
            int grow = ag * NCHN + row;
            grow = grow > (OUT_CH - 1) ? (OUT_CH - 1) : grow;
            gload16(Wb + (size_t)grow * C + k0 + scolBe, dst + (c << 10));
        }
    };

    auto compute = [&](int s) {
        const char* bb = smem + 65536 + (s & 1) * 16384;
        const int kt = s & ktMask;
        #pragma unroll
        for (int kk = 0; kk < 2; ++kk) {
            const int ca  = ((kt << 7) + (kk << 6) + kqb) ^ swzR;
            const int cbB = ((kk << 6) + kqb) ^ swzR;
            short8 af[2], bfr[3];
            #pragma unroll
            for (int i = 0; i < 2; ++i)
                if (i < MI) af[i] = *(const short8*)(smem + rowAb[i] + ca);
            #pragma unroll
            for (int j = 0; j < 3; ++j)
                bfr[j] = *(const short8*)(bb + rowBb[j] + cbB);
            #pragma unroll
            for (int i = 0; i < 2; ++i)
                if (i < MI)
                    #pragma unroll
                    for (int j = 0; j < 3; ++j)
                        acc[i][j] = __builtin_amdgcn_mfma_f32_16x16x32_bf16(af[i], bfr[j], acc[i][j], 0, 0, 0);
        }
    };

    const int rq = (lane >> 4) * 4;
    const int nf4 = lvl1 ? 1376 : 2752;

    auto epilogue = [&](int aL) {
        const int ag = aBase + aL;
        const int shp  = ag / 6;
        const int angi = ag - shp * 6;
        const float aw = lvl1 ? ((shp == 0) ? 30.f : (shp == 1) ? 62.f : 59.f)
                              : ((shp == 0) ? 10.f : (shp == 1) ? 16.f : 33.f);
        const float ah = lvl1 ? ((shp == 0) ? 61.f : (shp == 1) ? 45.f : 119.f)
                              : ((shp == 0) ? 13.f : (shp == 1) ? 30.f : 23.f);
        const float aa = (angi == 0) ? -1.04719755119659775f :
                         (angi == 1) ? -0.52359877559829887f :
                         (angi == 2) ?  0.0f :
                         (angi == 3) ?  0.52359877559829887f :
                         (angi == 4) ?  1.04719755119659775f :
                                        1.57079632679489662f;
        #pragma unroll
        for (int j = 0; j < 3; ++j) {
            const int ch = wn * 48 + j * 16 + lr;
            if (ch < NCHN) {
                const float bv = sBias[aL * NCHN + ch];
                #pragma unroll
                for (int i = 0; i < 2; ++i) {
                    if (i >= MI) continue;
                    #pragma unroll
                    for (int r = 0; r < 4; ++r) {
                        const int px = wm * MROWS + i * 16 + rq + r;
                        const int p  = p0 + px;
                        const float vv = acc[i][j][r] + bv;
                        float res;
                        if (ch == 0)      res = (sigm(vv) * sxy - sxy_off + (float)(p & ((1 << Gsh) - 1))) * sf;
                        else if (ch == 1) res = (sigm(vv) * sxy - sxy_off + (float)(p >> Gsh)) * sf;
                        else if (ch == 2) res = __expf(vv) * aw;
                        else if (ch == 3) res = __expf(vv) * ah;
                        else if (ch == 4) res = vv + aa;
                        else              res = sigm(vv);
                        sOutF[px * NCHN + ch] = res;
                    }
                }
            }
        }
        asm volatile("s_waitcnt lgkmcnt(0)" ::: "memory");
        __builtin_amdgcn_s_barrier();
        const size_t span = (size_t)b * BPB + ((size_t)(lvloff + ag * GG + p0)) * NCHN;
        #pragma unroll
        for (int k = 0; k < 6; ++k) {
            const int f4 = tid + k * 512;
            if (f4 < nf4) {
                const f32x4 vv = *(const f32x4*)&sOutF[f4 * 4];
                __builtin_nontemporal_store(vv, (f32x4*)&out[span + (size_t)f4 * 4]);
            }
        }
        // stores drained (<=2 outstanding = the in-flight B prefetch);
        // image reads into regs are complete (data-dep of issued stores).
        asm volatile("s_waitcnt vmcnt(2)" ::: "memory");
        __builtin_amdgcn_s_barrier();
        #pragma unroll
        for (int i = 0; i < 2; ++i)
            #pragma unroll
            for (int j = 0; j < 3; ++j)
                acc[i][j] = f32x4{0.f, 0.f, 0.f, 0.f};
    };

    // ---- prologue: A (8 loads) + B(s0) + B(s1); wait A+s0, keep s1 in flight ----
    #pragma unroll
    for (int i = 0; i < 8; ++i)
        gload16(Xp + (size_t)(i * rpiA + rowAin) * C + scolAe, smem + i * 8192 + tid * 16);
    stageB(0);
    stageB(1);
    asm volatile("s_waitcnt lgkmcnt(0)" ::: "memory");   // sBias ds_writes visible
    asm volatile("s_waitcnt vmcnt(2)" ::: "memory");
    __builtin_amdgcn_s_barrier();

    // ---- main pipelined loop: s = anchor*KT + kt ----
    const int S = 9 << ktsh;
    for (int s = 0; s < S; ++s) {
        compute(s);
        __builtin_amdgcn_s_barrier();               // all waves done reading buf s&1
        if (s + 2 < S) {
            stageB(s + 2);                          // overwrites buf s&1
            asm volatile("s_waitcnt vmcnt(2)" ::: "memory");   // stage(s+1) done
        } else {
            asm volatile("s_waitcnt vmcnt(0)" ::: "memory");
        }
        __builtin_amdgcn_s_barrier();
        if ((s & ktMask) == ktMask) epilogue(s >> ktsh);
    }
}

extern "C" void kernel_launch(void* const* d_in, const int* in_sizes, int n_in,
                              void* d_out, int out_size, void* d_ws, size_t ws_size,
                              hipStream_t stream) {
    const float* x0 = (const float*)d_in[0];
    const float* x1 = (const float*)d_in[1];
    const float* W0 = (const float*)d_in[2];
    const float* b0 = (const float*)d_in[3];
    const float* W1 = (const float*)d_in[4];
    const float* b1 = (const float*)d_in[5];
    float* out = (float*)d_out;

    constexpr size_t XB0_OFF = 0;            // 8*4096*256*2  = 16777216
    constexpr size_t XB1_OFF = 16777216;     // 8*1024*512*2  =  8388608
    constexpr size_t WB0_OFF = 25165824;     // 1548*256*2    =   792576
    constexpr size_t WB1_OFF = 25958400;     // 1548*512*2    =  1585152

    unsigned short* Xb0 = (unsigned short*)((char*)d_ws + XB0_OFF);
    unsigned short* Xb1 = (unsigned short*)((char*)d_ws + XB1_OFF);
    unsigned short* Wb0 = (unsigned short*)((char*)d_ws + WB0_OFF);
    unsigned short* Wb1 = (unsigned short*)((char*)d_ws + WB1_OFF);

    hipLaunchKernelGGL(conv_w_kernel, dim3((297216 + 255) / 256), dim3(256), 0, stream,
                       W0, Wb0, W1, Wb1);
    hipLaunchKernelGGL(transpose_x_kernel, dim3(64, 4, 8), dim3(256), 0, stream,
                       x0, Xb0, 256, 4096);
    hipLaunchKernelGGL(transpose_x_kernel, dim3(16, 8, 8), dim3(256), 0, stream,
                       x1, Xb1, 512, 1024);

    // lvl0: 256 mtiles(128px) x 2 anchor-groups = 512 blocks;
    // lvl1: 128 mtiles(64px)  x 2 anchor-groups = 256 blocks. Total 768.
    hipLaunchKernelGGL(detect_gemm, dim3(768), dim3(512), 0, stream,
                       Xb0, Xb1, Wb0, Wb1, b0, b1, out);
}